// Round 1
// baseline (729.449 us; speedup 1.0000x reference)
//
#include <hip/hip_runtime.h>
#include <hip/hip_bf16.h>
#include <stdint.h>

// SelfAttention: x[4,2048,1024] fp32; q=xWq+bq, k=xWk+bk, v=xWv+bv;
// out = softmax(q k^T / 32) v.  All GEMMs via split-bf16 (hi/lo) 3-term MFMA
// for fp32-class accuracy on bf16 matrix cores.

typedef short bf16x8 __attribute__((ext_vector_type(8)));
typedef float f32x4 __attribute__((ext_vector_type(4)));
typedef unsigned short us4 __attribute__((ext_vector_type(4)));

#define B_ 4
#define S_ 2048
#define D_ 1024

__device__ __forceinline__ float bf2f(unsigned short h) {
  return __uint_as_float(((unsigned int)h) << 16);
}
__device__ __forceinline__ unsigned short f2bf(float f) {
  unsigned int u = __float_as_uint(f);
  unsigned int r = (u + 0x7fffu + ((u >> 16) & 1u)) >> 16;  // RNE
  return (unsigned short)r;
}
__device__ __forceinline__ void split2(float f, unsigned short& h, unsigned short& l) {
  h = f2bf(f);
  float r = f - bf2f(h);   // exact (hi has 8-bit mantissa)
  l = f2bf(r);
}

// async global->LDS, 16B per lane. lds addr must be wave-uniform; global is per-lane.
__device__ __forceinline__ void gl2lds16(void* lds, const void* g) {
  __builtin_amdgcn_global_load_lds(
      (const __attribute__((address_space(1))) unsigned int*)(uintptr_t)g,
      (__attribute__((address_space(3))) unsigned int*)(uintptr_t)lds,
      16, 0, 0);
}

// Copy a 128-row x 64-byte tile (global row stride = stride_bytes) into linear LDS [128][64B].
__device__ __forceinline__ void stage128x64(void* lds, const void* g, int stride_bytes,
                                            int wave, int lane) {
  const char* gc = (const char*)g;
  char* lc = (char*)lds;
#pragma unroll
  for (int i = 0; i < 2; ++i) {
    int rbase = wave * 32 + i * 16;
    int row = rbase + (lane >> 2);
    gl2lds16(lc + rbase * 64,
             gc + (size_t)row * stride_bytes + (size_t)(lane & 3) * 16);
  }
}

// One K-step (BK=32) of the 128x128 tile: 4x4 fragments of 16x16x32 per wave,
// 3-term split MFMA. LDS layout: [128 rows][32 k] bf16, linear.
__device__ __forceinline__ void mfma_block(const unsigned short* ah, const unsigned short* al,
                                           const unsigned short* bh, const unsigned short* bl,
                                           f32x4 acc[4][4], int lane, int wm, int wn) {
  int r15 = lane & 15, kg = lane >> 4;
  bf16x8 A_h[4], A_l[4], B_h[4], B_l[4];
#pragma unroll
  for (int f = 0; f < 4; ++f) {
    int aoff = (wm * 64 + f * 16 + r15) * 32 + kg * 8;
    A_h[f] = *(const bf16x8*)(ah + aoff);
    A_l[f] = *(const bf16x8*)(al + aoff);
    int boff = (wn * 64 + f * 16 + r15) * 32 + kg * 8;
    B_h[f] = *(const bf16x8*)(bh + boff);
    B_l[f] = *(const bf16x8*)(bl + boff);
  }
#pragma unroll
  for (int i = 0; i < 4; ++i)
#pragma unroll
    for (int j = 0; j < 4; ++j) {
      acc[i][j] = __builtin_amdgcn_mfma_f32_16x16x32_bf16(A_h[i], B_h[j], acc[i][j], 0, 0, 0);
      acc[i][j] = __builtin_amdgcn_mfma_f32_16x16x32_bf16(A_h[i], B_l[j], acc[i][j], 0, 0, 0);
      acc[i][j] = __builtin_amdgcn_mfma_f32_16x16x32_bf16(A_l[i], B_h[j], acc[i][j], 0, 0, 0);
    }
}

// ---------------- kernel 1: W [k][n] fp32 -> Wt hi/lo bf16 planes [n][k] ----------------
__global__ __launch_bounds__(256) void wt_prep(const float* __restrict__ Wq,
                                               const float* __restrict__ Wk,
                                               const float* __restrict__ Wv,
                                               unsigned short* __restrict__ wth,
                                               unsigned short* __restrict__ wtl) {
  __shared__ unsigned short hs[64][65];
  __shared__ unsigned short ls[64][65];
  int mat = blockIdx.z;
  const float* W = (mat == 0) ? Wq : (mat == 1) ? Wk : Wv;
  int n0 = blockIdx.x * 64, k0 = blockIdx.y * 64;
  int tid = threadIdx.x;
#pragma unroll
  for (int i = 0; i < 16; ++i) {
    int idx = tid + i * 256;
    int r = idx >> 6, c = idx & 63;  // r: k, c: n
    float f = W[(size_t)(k0 + r) * D_ + (n0 + c)];
    unsigned short h, l;
    split2(f, h, l);
    hs[r][c] = h; ls[r][c] = l;
  }
  __syncthreads();
  unsigned short* oh = wth + ((size_t)mat << 20);
  unsigned short* ol = wtl + ((size_t)mat << 20);
#pragma unroll
  for (int i = 0; i < 16; ++i) {
    int idx = tid + i * 256;
    int r = idx >> 6, c = idx & 63;  // r: n, c: k
    oh[(size_t)(n0 + r) * D_ + (k0 + c)] = hs[c][r];
    ol[(size_t)(n0 + r) * D_ + (k0 + c)] = ls[c][r];
  }
}

// ---------------- kernel 2: QKV projection GEMM ----------------
// C[m][n] = sum_k x[m][k] * Wt[n][k] + bias[n], M=8192, N=K=1024. z selects mat.
__global__ __launch_bounds__(256) void qkv_gemm(const float* __restrict__ x,
    const unsigned short* __restrict__ wth, const unsigned short* __restrict__ wtl,
    const float* __restrict__ bq, const float* __restrict__ bk, const float* __restrict__ bv,
    unsigned short* __restrict__ qh, unsigned short* __restrict__ ql,
    unsigned short* __restrict__ kh, unsigned short* __restrict__ kl,
    unsigned short* __restrict__ vh, unsigned short* __restrict__ vl) {
  __shared__ __align__(16) unsigned short ah[128 * 32];
  __shared__ __align__(16) unsigned short al[128 * 32];
  __shared__ __align__(16) unsigned short bh[128 * 32];
  __shared__ __align__(16) unsigned short bl[128 * 32];
  int tid = threadIdx.x, lane = tid & 63, wave = tid >> 6;
  int wm = wave >> 1, wn = wave & 1;
  int m0 = blockIdx.x * 128, n0 = blockIdx.y * 128;
  int mat = blockIdx.z;
  const unsigned short* wh = wth + ((size_t)mat << 20);
  const unsigned short* wl = wtl + ((size_t)mat << 20);
  const float* bias = (mat == 0) ? bq : (mat == 1) ? bk : bv;
  unsigned short* oh = (mat == 0) ? qh : (mat == 1) ? kh : vh;
  unsigned short* ol = (mat == 0) ? ql : (mat == 1) ? kl : vl;

  f32x4 acc[4][4] = {};
  for (int kk = 0; kk < D_; kk += 32) {
    // B: pre-split Wt planes, async direct to LDS
    stage128x64(bh, wh + (size_t)n0 * D_ + kk, D_ * 2, wave, lane);
    stage128x64(bl, wl + (size_t)n0 * D_ + kk, D_ * 2, wave, lane);
    // A: fp32 x -> hi/lo bf16 in LDS (2 segments of 8 k per thread)
#pragma unroll
    for (int i = 0; i < 2; ++i) {
      int s = tid + i * 256;
      int row = s >> 2, k8 = s & 3;
      const float* gp = x + (size_t)(m0 + row) * D_ + kk + k8 * 8;
      float4 f0 = *(const float4*)gp;
      float4 f1 = *(const float4*)(gp + 4);
      float vals[8] = {f0.x, f0.y, f0.z, f0.w, f1.x, f1.y, f1.z, f1.w};
      union { bf16x8 v; unsigned short s_[8]; } H, L;
#pragma unroll
      for (int e = 0; e < 8; ++e) split2(vals[e], H.s_[e], L.s_[e]);
      *(bf16x8*)(ah + row * 32 + k8 * 8) = H.v;
      *(bf16x8*)(al + row * 32 + k8 * 8) = L.v;
    }
    __syncthreads();
    mfma_block(ah, al, bh, bl, acc, lane, wm, wn);
    __syncthreads();
  }
#pragma unroll
  for (int fi = 0; fi < 4; ++fi)
#pragma unroll
    for (int fj = 0; fj < 4; ++fj) {
      int col = n0 + wn * 64 + fj * 16 + (lane & 15);
      float bb = bias[col];
#pragma unroll
      for (int r = 0; r < 4; ++r) {
        int row = m0 + wm * 64 + fi * 16 + (lane >> 4) * 4 + r;
        float v = acc[fi][fj][r] + bb;
        unsigned short h, l;
        split2(v, h, l);
        oh[(size_t)row * D_ + col] = h;
        ol[(size_t)row * D_ + col] = l;
      }
    }
}

// ---------------- kernel 3: v [b][t][d] -> vT [b][d][t] (both hi & lo planes) ----------------
__global__ __launch_bounds__(256) void vtrans(const unsigned short* __restrict__ vinh,
                                              const unsigned short* __restrict__ vinl,
                                              unsigned short* __restrict__ vouth,
                                              unsigned short* __restrict__ voutl) {
  int bz = blockIdx.z, b = bz >> 1, pl = bz & 1;
  const unsigned short* vin = (pl ? vinl : vinh) + (size_t)b * S_ * D_;
  unsigned short* vout = (pl ? voutl : vouth) + (size_t)b * D_ * S_;
  int d0 = blockIdx.x * 64, t0 = blockIdx.y * 64;
  __shared__ unsigned short ts[64][72];
  int tid = threadIdx.x;
#pragma unroll
  for (int i = 0; i < 16; ++i) {
    int idx = tid + i * 256;
    int r = idx >> 6, c = idx & 63;  // r: t, c: d
    ts[r][c] = vin[(size_t)(t0 + r) * D_ + d0 + c];
  }
  __syncthreads();
#pragma unroll
  for (int i = 0; i < 16; ++i) {
    int idx = tid + i * 256;
    int r = idx >> 6, c = idx & 63;  // r: d, c: t
    vout[(size_t)(d0 + r) * S_ + t0 + c] = ts[c][r];
  }
}

// ---------------- kernel 4: scores = q k^T / 32 (one batch) ----------------
__global__ __launch_bounds__(256) void s2_gemm(const unsigned short* __restrict__ qh,
                                               const unsigned short* __restrict__ ql,
                                               const unsigned short* __restrict__ kh,
                                               const unsigned short* __restrict__ kl,
                                               float* __restrict__ scores) {
  __shared__ __align__(16) unsigned short ah[128 * 32];
  __shared__ __align__(16) unsigned short al[128 * 32];
  __shared__ __align__(16) unsigned short bh[128 * 32];
  __shared__ __align__(16) unsigned short bl[128 * 32];
  int tid = threadIdx.x, lane = tid & 63, wave = tid >> 6;
  int wm = wave >> 1, wn = wave & 1;
  int m0 = blockIdx.x * 128, n0 = blockIdx.y * 128;
  f32x4 acc[4][4] = {};
  for (int kk = 0; kk < D_; kk += 32) {
    stage128x64(ah, qh + (size_t)m0 * D_ + kk, D_ * 2, wave, lane);
    stage128x64(al, ql + (size_t)m0 * D_ + kk, D_ * 2, wave, lane);
    stage128x64(bh, kh + (size_t)n0 * D_ + kk, D_ * 2, wave, lane);
    stage128x64(bl, kl + (size_t)n0 * D_ + kk, D_ * 2, wave, lane);
    __syncthreads();
    mfma_block(ah, al, bh, bl, acc, lane, wm, wn);
    __syncthreads();
  }
#pragma unroll
  for (int fi = 0; fi < 4; ++fi)
#pragma unroll
    for (int fj = 0; fj < 4; ++fj) {
      int col = n0 + wn * 64 + fj * 16 + (lane & 15);
#pragma unroll
      for (int r = 0; r < 4; ++r) {
        int row = m0 + wm * 64 + fi * 16 + (lane >> 4) * 4 + r;
        scores[(size_t)row * S_ + col] = acc[fi][fj][r] * 0.03125f;
      }
    }
}

// ---------------- kernel 5: row softmax, scores fp32 -> P hi/lo planes ----------------
__global__ __launch_bounds__(256) void softmax_k(const float* __restrict__ scores,
                                                 unsigned short* __restrict__ ph,
                                                 unsigned short* __restrict__ plo) {
  int row = blockIdx.x, tid = threadIdx.x, lane = tid & 63, wave = tid >> 6;
  const float* s = scores + (size_t)row * S_;
  float4 a = ((const float4*)s)[tid];
  float4 b = ((const float4*)s)[256 + tid];
  float m = fmaxf(fmaxf(fmaxf(a.x, a.y), fmaxf(a.z, a.w)),
                  fmaxf(fmaxf(b.x, b.y), fmaxf(b.z, b.w)));
#pragma unroll
  for (int o = 32; o; o >>= 1) m = fmaxf(m, __shfl_xor(m, o));
  __shared__ float red[4];
  if (lane == 0) red[wave] = m;
  __syncthreads();
  m = fmaxf(fmaxf(red[0], red[1]), fmaxf(red[2], red[3]));
  float p[8] = {expf(a.x - m), expf(a.y - m), expf(a.z - m), expf(a.w - m),
                expf(b.x - m), expf(b.y - m), expf(b.z - m), expf(b.w - m)};
  float sum = 0.f;
#pragma unroll
  for (int e = 0; e < 8; ++e) sum += p[e];
#pragma unroll
  for (int o = 32; o; o >>= 1) sum += __shfl_xor(sum, o);
  __syncthreads();  // all reads of red done before reuse
  if (lane == 0) red[wave] = sum;
  __syncthreads();
  float inv = 1.0f / (red[0] + red[1] + red[2] + red[3]);
  unsigned short h[8], l[8];
#pragma unroll
  for (int e = 0; e < 8; ++e) split2(p[e] * inv, h[e], l[e]);
  size_t base = (size_t)row * S_;
  *(us4*)(ph + base + tid * 4) = (us4){h[0], h[1], h[2], h[3]};
  *(us4*)(ph + base + 1024 + tid * 4) = (us4){h[4], h[5], h[6], h[7]};
  *(us4*)(plo + base + tid * 4) = (us4){l[0], l[1], l[2], l[3]};
  *(us4*)(plo + base + 1024 + tid * 4) = (us4){l[4], l[5], l[6], l[7]};
}

// ---------------- kernel 6: out = P vT (one batch), K = 2048 ----------------
__global__ __launch_bounds__(256) void s3_gemm(const unsigned short* __restrict__ ph,
                                               const unsigned short* __restrict__ plo,
                                               const unsigned short* __restrict__ vth,
                                               const unsigned short* __restrict__ vtl,
                                               float* __restrict__ out) {
  __shared__ __align__(16) unsigned short ah[128 * 32];
  __shared__ __align__(16) unsigned short al[128 * 32];
  __shared__ __align__(16) unsigned short bh[128 * 32];
  __shared__ __align__(16) unsigned short bl[128 * 32];
  int tid = threadIdx.x, lane = tid & 63, wave = tid >> 6;
  int wm = wave >> 1, wn = wave & 1;
  int m0 = blockIdx.x * 128, n0 = blockIdx.y * 128;
  f32x4 acc[4][4] = {};
  for (int kk = 0; kk < S_; kk += 32) {
    stage128x64(ah, ph + (size_t)m0 * S_ + kk, S_ * 2, wave, lane);
    stage128x64(al, plo + (size_t)m0 * S_ + kk, S_ * 2, wave, lane);
    stage128x64(bh, vth + (size_t)n0 * S_ + kk, S_ * 2, wave, lane);
    stage128x64(bl, vtl + (size_t)n0 * S_ + kk, S_ * 2, wave, lane);
    __syncthreads();
    mfma_block(ah, al, bh, bl, acc, lane, wm, wn);
    __syncthreads();
  }
#pragma unroll
  for (int fi = 0; fi < 4; ++fi)
#pragma unroll
    for (int fj = 0; fj < 4; ++fj) {
      int col = n0 + wn * 64 + fj * 16 + (lane & 15);
#pragma unroll
      for (int r = 0; r < 4; ++r) {
        int row = m0 + wm * 64 + fi * 16 + (lane >> 4) * 4 + r;
        out[(size_t)row * D_ + col] = acc[fi][fj][r];
      }
    }
}

extern "C" void kernel_launch(void* const* d_in, const int* in_sizes, int n_in,
                              void* d_out, int out_size, void* d_ws, size_t ws_size,
                              hipStream_t stream) {
  const float* x  = (const float*)d_in[0];
  const float* Wq = (const float*)d_in[1];
  const float* bq = (const float*)d_in[2];
  const float* Wk = (const float*)d_in[3];
  const float* bk = (const float*)d_in[4];
  const float* Wv = (const float*)d_in[5];
  const float* bv = (const float*)d_in[6];
  float* out = (float*)d_out;
  char* ws = (char*)d_ws;
  const size_t MB = 1024 * 1024;
  // workspace layout (total 140 MiB; scores/P safely reuse v_tmp after vtrans)
  unsigned short* qh  = (unsigned short*)(ws + 0 * MB);
  unsigned short* ql  = (unsigned short*)(ws + 16 * MB);
  unsigned short* kh  = (unsigned short*)(ws + 32 * MB);
  unsigned short* kl  = (unsigned short*)(ws + 48 * MB);
  unsigned short* vth = (unsigned short*)(ws + 64 * MB);
  unsigned short* vtl = (unsigned short*)(ws + 80 * MB);
  unsigned short* wth = (unsigned short*)(ws + 96 * MB);
  unsigned short* wtl = (unsigned short*)(ws + 102 * MB);
  unsigned short* vtmp_h = (unsigned short*)(ws + 108 * MB);
  unsigned short* vtmp_l = (unsigned short*)(ws + 124 * MB);
  float* scores       = (float*)(ws + 108 * MB);           // reuse of vtmp_h
  unsigned short* ph  = (unsigned short*)(ws + 124 * MB);  // reuse of vtmp_l
  unsigned short* plo = (unsigned short*)(ws + 132 * MB);

  wt_prep<<<dim3(16, 16, 3), 256, 0, stream>>>(Wq, Wk, Wv, wth, wtl);
  qkv_gemm<<<dim3(64, 8, 3), 256, 0, stream>>>(x, wth, wtl, bq, bk, bv,
                                               qh, ql, kh, kl, vtmp_h, vtmp_l);
  vtrans<<<dim3(16, 32, 8), 256, 0, stream>>>(vtmp_h, vtmp_l, vth, vtl);
  for (int b = 0; b < B_; ++b) {
    size_t o = (size_t)b * S_ * D_;
    size_t ot = (size_t)b * D_ * S_;
    s2_gemm<<<dim3(16, 16), 256, 0, stream>>>(qh + o, ql + o, kh + o, kl + o, scores);
    softmax_k<<<dim3(S_), 256, 0, stream>>>(scores, ph, plo);
    s3_gemm<<<dim3(16, 8), 256, 0, stream>>>(ph, plo, vth + ot, vtl + ot, out + o);
  }
}

// Round 2
// 408.954 us; speedup vs baseline: 1.7837x; 1.7837x over previous
//
#include <hip/hip_runtime.h>
#include <hip/hip_bf16.h>
#include <stdint.h>

// SelfAttention: x[4,2048,1024] fp32; q=xWq+bq, k=xWk+bk, v=xWv+bv;
// out = softmax(q k^T / 32) v.  All GEMMs via split-bf16 (hi/lo) 3-term MFMA.
// R2: pre-split x (kills in-loop VALU conversion), batch attention stages,
// fp16 scores. ws-size-adaptive layout (batched needs 236 MiB, fallback 140).

typedef short bf16x8 __attribute__((ext_vector_type(8)));
typedef float f32x4 __attribute__((ext_vector_type(4)));
typedef unsigned short us4 __attribute__((ext_vector_type(4)));
typedef _Float16 h4 __attribute__((ext_vector_type(4)));
typedef unsigned short us;

#define B_ 4
#define S_ 2048
#define D_ 1024

__device__ __forceinline__ float bf2f(us h) {
  return __uint_as_float(((unsigned int)h) << 16);
}
__device__ __forceinline__ us f2bf(float f) {
  unsigned int u = __float_as_uint(f);
  unsigned int r = (u + 0x7fffu + ((u >> 16) & 1u)) >> 16;  // RNE
  return (us)r;
}
__device__ __forceinline__ void split2(float f, us& h, us& l) {
  h = f2bf(f);
  float r = f - bf2f(h);   // exact (hi has 8-bit mantissa)
  l = f2bf(r);
}

// async global->LDS, 16B per lane. lds addr wave-uniform; global per-lane.
__device__ __forceinline__ void gl2lds16(void* lds, const void* g) {
  __builtin_amdgcn_global_load_lds(
      (const __attribute__((address_space(1))) unsigned int*)(uintptr_t)g,
      (__attribute__((address_space(3))) unsigned int*)(uintptr_t)lds,
      16, 0, 0);
}

// 128-row x 64-byte tile (global row stride = stride_bytes) -> linear LDS [128][64B].
__device__ __forceinline__ void stage128x64(void* lds, const void* g, int stride_bytes,
                                            int wave, int lane) {
  const char* gc = (const char*)g;
  char* lc = (char*)lds;
#pragma unroll
  for (int i = 0; i < 2; ++i) {
    int rbase = wave * 32 + i * 16;
    int row = rbase + (lane >> 2);
    gl2lds16(lc + rbase * 64,
             gc + (size_t)row * stride_bytes + (size_t)(lane & 3) * 16);
  }
}

// One K-step (BK=32): 4x4 fragments of 16x16x32 per wave, 3-term split MFMA.
// LDS: [128 rows][32 k] bf16 linear.
__device__ __forceinline__ void mfma_block(const us* ah, const us* al,
                                           const us* bh, const us* bl,
                                           f32x4 acc[4][4], int lane, int wm, int wn) {
  int r15 = lane & 15, kg = lane >> 4;
  bf16x8 A_h[4], A_l[4], B_h[4], B_l[4];
#pragma unroll
  for (int f = 0; f < 4; ++f) {
    int aoff = (wm * 64 + f * 16 + r15) * 32 + kg * 8;
    A_h[f] = *(const bf16x8*)(ah + aoff);
    A_l[f] = *(const bf16x8*)(al + aoff);
    int boff = (wn * 64 + f * 16 + r15) * 32 + kg * 8;
    B_h[f] = *(const bf16x8*)(bh + boff);
    B_l[f] = *(const bf16x8*)(bl + boff);
  }
#pragma unroll
  for (int i = 0; i < 4; ++i)
#pragma unroll
    for (int j = 0; j < 4; ++j) {
      acc[i][j] = __builtin_amdgcn_mfma_f32_16x16x32_bf16(A_h[i], B_h[j], acc[i][j], 0, 0, 0);
      acc[i][j] = __builtin_amdgcn_mfma_f32_16x16x32_bf16(A_h[i], B_l[j], acc[i][j], 0, 0, 0);
      acc[i][j] = __builtin_amdgcn_mfma_f32_16x16x32_bf16(A_l[i], B_h[j], acc[i][j], 0, 0, 0);
    }
}

// ---------------- W [k][n] fp32 -> Wt hi/lo bf16 planes [n][k] ----------------
__global__ __launch_bounds__(256) void wt_prep(const float* __restrict__ Wq,
                                               const float* __restrict__ Wk,
                                               const float* __restrict__ Wv,
                                               us* __restrict__ wth,
                                               us* __restrict__ wtl) {
  __shared__ us hs[64][65];
  __shared__ us ls[64][65];
  int mat = blockIdx.z;
  const float* W = (mat == 0) ? Wq : (mat == 1) ? Wk : Wv;
  int n0 = blockIdx.x * 64, k0 = blockIdx.y * 64;
  int tid = threadIdx.x;
#pragma unroll
  for (int i = 0; i < 16; ++i) {
    int idx = tid + i * 256;
    int r = idx >> 6, c = idx & 63;  // r: k, c: n
    float f = W[(size_t)(k0 + r) * D_ + (n0 + c)];
    us h, l;
    split2(f, h, l);
    hs[r][c] = h; ls[r][c] = l;
  }
  __syncthreads();
  us* oh = wth + ((size_t)mat << 20);
  us* ol = wtl + ((size_t)mat << 20);
#pragma unroll
  for (int i = 0; i < 16; ++i) {
    int idx = tid + i * 256;
    int r = idx >> 6, c = idx & 63;  // r: n, c: k
    oh[(size_t)(n0 + r) * D_ + (k0 + c)] = hs[c][r];
    ol[(size_t)(n0 + r) * D_ + (k0 + c)] = ls[c][r];
  }
}

// ---------------- x fp32 -> xh/xl bf16 planes (same [m][k] layout) ----------------
__global__ __launch_bounds__(256) void xsplit(const float* __restrict__ x,
                                              us* __restrict__ xh, us* __restrict__ xl) {
  size_t i = ((size_t)blockIdx.x * 256 + threadIdx.x) * 8;
  float4 f0 = *(const float4*)(x + i);
  float4 f1 = *(const float4*)(x + i + 4);
  float vals[8] = {f0.x, f0.y, f0.z, f0.w, f1.x, f1.y, f1.z, f1.w};
  union { bf16x8 v; us s_[8]; } H, L;
#pragma unroll
  for (int e = 0; e < 8; ++e) split2(vals[e], H.s_[e], L.s_[e]);
  *(bf16x8*)(xh + i) = H.v;
  *(bf16x8*)(xl + i) = L.v;
}

// ---------------- QKV projection: C[m][n] = x[m][:] . Wt[n][:] + bias[n] ----------------
__global__ __launch_bounds__(256) void qkv_gemm(
    const us* __restrict__ xh, const us* __restrict__ xl,
    const us* __restrict__ wth, const us* __restrict__ wtl,
    const float* __restrict__ bq, const float* __restrict__ bk, const float* __restrict__ bv,
    us* __restrict__ qh, us* __restrict__ ql,
    us* __restrict__ kh, us* __restrict__ kl,
    us* __restrict__ vh, us* __restrict__ vl) {
  __shared__ __align__(16) us ah[128 * 32];
  __shared__ __align__(16) us al[128 * 32];
  __shared__ __align__(16) us bh[128 * 32];
  __shared__ __align__(16) us bl[128 * 32];
  int tid = threadIdx.x, lane = tid & 63, wave = tid >> 6;
  int wm = wave >> 1, wn = wave & 1;
  int m0 = blockIdx.x * 128, n0 = blockIdx.y * 128;
  int mat = blockIdx.z;
  const us* wh = wth + ((size_t)mat << 20);
  const us* wl = wtl + ((size_t)mat << 20);
  const float* bias = (mat == 0) ? bq : (mat == 1) ? bk : bv;
  us* oh = (mat == 0) ? qh : (mat == 1) ? kh : vh;
  us* ol = (mat == 0) ? ql : (mat == 1) ? kl : vl;

  f32x4 acc[4][4] = {};
  for (int kk = 0; kk < D_; kk += 32) {
    stage128x64(ah, xh + (size_t)m0 * D_ + kk, D_ * 2, wave, lane);
    stage128x64(al, xl + (size_t)m0 * D_ + kk, D_ * 2, wave, lane);
    stage128x64(bh, wh + (size_t)n0 * D_ + kk, D_ * 2, wave, lane);
    stage128x64(bl, wl + (size_t)n0 * D_ + kk, D_ * 2, wave, lane);
    __syncthreads();
    mfma_block(ah, al, bh, bl, acc, lane, wm, wn);
    __syncthreads();
  }
#pragma unroll
  for (int fi = 0; fi < 4; ++fi)
#pragma unroll
    for (int fj = 0; fj < 4; ++fj) {
      int col = n0 + wn * 64 + fj * 16 + (lane & 15);
      float bb = bias[col];
#pragma unroll
      for (int r = 0; r < 4; ++r) {
        int row = m0 + wm * 64 + fi * 16 + (lane >> 4) * 4 + r;
        float v = acc[fi][fj][r] + bb;
        us h, l;
        split2(v, h, l);
        oh[(size_t)row * D_ + col] = h;
        ol[(size_t)row * D_ + col] = l;
      }
    }
}

// ---------------- v [b][t][d] -> vT [b][d][t] (hi & lo planes) ----------------
__global__ __launch_bounds__(256) void vtrans(const us* __restrict__ vinh,
                                              const us* __restrict__ vinl,
                                              us* __restrict__ vouth,
                                              us* __restrict__ voutl) {
  int bz = blockIdx.z, b = bz >> 1, pl = bz & 1;
  const us* vin = (pl ? vinl : vinh) + (size_t)b * S_ * D_;
  us* vout = (pl ? voutl : vouth) + (size_t)b * D_ * S_;
  int d0 = blockIdx.x * 64, t0 = blockIdx.y * 64;
  __shared__ us ts[64][72];
  int tid = threadIdx.x;
#pragma unroll
  for (int i = 0; i < 16; ++i) {
    int idx = tid + i * 256;
    int r = idx >> 6, c = idx & 63;  // r: t, c: d
    ts[r][c] = vin[(size_t)(t0 + r) * D_ + d0 + c];
  }
  __syncthreads();
#pragma unroll
  for (int i = 0; i < 16; ++i) {
    int idx = tid + i * 256;
    int r = idx >> 6, c = idx & 63;  // r: d, c: t
    vout[(size_t)(d0 + r) * S_ + t0 + c] = ts[c][r];
  }
}

// ---------------- scores = q k^T / 32, fp16 out. z = batch ----------------
__global__ __launch_bounds__(256) void s2_gemm(const us* __restrict__ qh,
                                               const us* __restrict__ ql,
                                               const us* __restrict__ kh,
                                               const us* __restrict__ kl,
                                               _Float16* __restrict__ scores) {
  __shared__ __align__(16) us ah[128 * 32];
  __shared__ __align__(16) us al[128 * 32];
  __shared__ __align__(16) us bh[128 * 32];
  __shared__ __align__(16) us bl[128 * 32];
  int tid = threadIdx.x, lane = tid & 63, wave = tid >> 6;
  int wm = wave >> 1, wn = wave & 1;
  int m0 = blockIdx.x * 128, n0 = blockIdx.y * 128;
  size_t b = blockIdx.z;
  const us* qh_b = qh + b * (size_t)(S_ * D_);
  const us* ql_b = ql + b * (size_t)(S_ * D_);
  const us* kh_b = kh + b * (size_t)(S_ * D_);
  const us* kl_b = kl + b * (size_t)(S_ * D_);
  _Float16* sc = scores + b * (size_t)(S_ * S_);
  f32x4 acc[4][4] = {};
  for (int kk = 0; kk < D_; kk += 32) {
    stage128x64(ah, qh_b + (size_t)m0 * D_ + kk, D_ * 2, wave, lane);
    stage128x64(al, ql_b + (size_t)m0 * D_ + kk, D_ * 2, wave, lane);
    stage128x64(bh, kh_b + (size_t)n0 * D_ + kk, D_ * 2, wave, lane);
    stage128x64(bl, kl_b + (size_t)n0 * D_ + kk, D_ * 2, wave, lane);
    __syncthreads();
    mfma_block(ah, al, bh, bl, acc, lane, wm, wn);
    __syncthreads();
  }
#pragma unroll
  for (int fi = 0; fi < 4; ++fi)
#pragma unroll
    for (int fj = 0; fj < 4; ++fj) {
      int col = n0 + wn * 64 + fj * 16 + (lane & 15);
#pragma unroll
      for (int r = 0; r < 4; ++r) {
        int row = m0 + wm * 64 + fi * 16 + (lane >> 4) * 4 + r;
        sc[(size_t)row * S_ + col] = (_Float16)(acc[fi][fj][r] * 0.03125f);
      }
    }
}

// ---------------- row softmax: fp16 scores -> P hi/lo planes ----------------
__global__ __launch_bounds__(256) void softmax_k(const _Float16* __restrict__ scores,
                                                 us* __restrict__ ph,
                                                 us* __restrict__ plo) {
  int row = blockIdx.x, tid = threadIdx.x, lane = tid & 63, wave = tid >> 6;
  const _Float16* s = scores + (size_t)row * S_;
  h4 a4 = ((const h4*)s)[tid];
  h4 b4 = ((const h4*)s)[256 + tid];
  float a[8] = {(float)a4.x, (float)a4.y, (float)a4.z, (float)a4.w,
                (float)b4.x, (float)b4.y, (float)b4.z, (float)b4.w};
  float m = a[0];
#pragma unroll
  for (int e = 1; e < 8; ++e) m = fmaxf(m, a[e]);
#pragma unroll
  for (int o = 32; o; o >>= 1) m = fmaxf(m, __shfl_xor(m, o));
  __shared__ float red[4];
  if (lane == 0) red[wave] = m;
  __syncthreads();
  m = fmaxf(fmaxf(red[0], red[1]), fmaxf(red[2], red[3]));
  float p[8];
  float sum = 0.f;
#pragma unroll
  for (int e = 0; e < 8; ++e) { p[e] = expf(a[e] - m); sum += p[e]; }
#pragma unroll
  for (int o = 32; o; o >>= 1) sum += __shfl_xor(sum, o);
  __syncthreads();  // all reads of red done before reuse
  if (lane == 0) red[wave] = sum;
  __syncthreads();
  float inv = 1.0f / (red[0] + red[1] + red[2] + red[3]);
  us h[8], l[8];
#pragma unroll
  for (int e = 0; e < 8; ++e) split2(p[e] * inv, h[e], l[e]);
  size_t base = (size_t)row * S_;
  *(us4*)(ph + base + tid * 4) = (us4){h[0], h[1], h[2], h[3]};
  *(us4*)(ph + base + 1024 + tid * 4) = (us4){h[4], h[5], h[6], h[7]};
  *(us4*)(plo + base + tid * 4) = (us4){l[0], l[1], l[2], l[3]};
  *(us4*)(plo + base + 1024 + tid * 4) = (us4){l[4], l[5], l[6], l[7]};
}

// ---------------- out = P vT, K = 2048. z = batch ----------------
__global__ __launch_bounds__(256) void s3_gemm(const us* __restrict__ ph,
                                               const us* __restrict__ plo,
                                               const us* __restrict__ vth,
                                               const us* __restrict__ vtl,
                                               float* __restrict__ out) {
  __shared__ __align__(16) us ah[128 * 32];
  __shared__ __align__(16) us al[128 * 32];
  __shared__ __align__(16) us bh[128 * 32];
  __shared__ __align__(16) us bl[128 * 32];
  int tid = threadIdx.x, lane = tid & 63, wave = tid >> 6;
  int wm = wave >> 1, wn = wave & 1;
  int m0 = blockIdx.x * 128, n0 = blockIdx.y * 128;
  size_t b = blockIdx.z;
  const us* pa = ph + b * (size_t)(S_ * S_);
  const us* pb = plo + b * (size_t)(S_ * S_);
  const us* vh_b = vth + b * (size_t)(D_ * S_);
  const us* vl_b = vtl + b * (size_t)(D_ * S_);
  float* out_b = out + b * (size_t)(S_ * D_);
  f32x4 acc[4][4] = {};
  for (int kk = 0; kk < S_; kk += 32) {
    stage128x64(ah, pa + (size_t)m0 * S_ + kk, S_ * 2, wave, lane);
    stage128x64(al, pb + (size_t)m0 * S_ + kk, S_ * 2, wave, lane);
    stage128x64(bh, vh_b + (size_t)n0 * S_ + kk, S_ * 2, wave, lane);
    stage128x64(bl, vl_b + (size_t)n0 * S_ + kk, S_ * 2, wave, lane);
    __syncthreads();
    mfma_block(ah, al, bh, bl, acc, lane, wm, wn);
    __syncthreads();
  }
#pragma unroll
  for (int fi = 0; fi < 4; ++fi)
#pragma unroll
    for (int fj = 0; fj < 4; ++fj) {
      int col = n0 + wn * 64 + fj * 16 + (lane & 15);
#pragma unroll
      for (int r = 0; r < 4; ++r) {
        int row = m0 + wm * 64 + fi * 16 + (lane >> 4) * 4 + r;
        out_b[(size_t)row * D_ + col] = acc[fi][fj][r];
      }
    }
}

extern "C" void kernel_launch(void* const* d_in, const int* in_sizes, int n_in,
                              void* d_out, int out_size, void* d_ws, size_t ws_size,
                              hipStream_t stream) {
  const float* x  = (const float*)d_in[0];
  const float* Wq = (const float*)d_in[1];
  const float* bq = (const float*)d_in[2];
  const float* Wk = (const float*)d_in[3];
  const float* bk = (const float*)d_in[4];
  const float* Wv = (const float*)d_in[5];
  const float* bv = (const float*)d_in[6];
  float* out = (float*)d_out;
  char* ws = (char*)d_ws;
  const size_t MB = 1024 * 1024;
  // Layout (lifetime-overlapped):
  //  [0,64)    qh ql kh kl           (qkv -> s2)
  //  [64,96)   vtmp h/l              (qkv -> vtrans); dead after -> compact scores/P
  //  [96,108)  wth wtl               (wt_prep -> qkv); dead after
  //  [108,140) xh xl                 (xsplit -> qkv); dead after
  //  [96,128)  vth vtl               (vtrans -> s3), reuses dead w/x region
  //  batched:  [140,172) scores fp16, [172,204) ph, [204,236) plo
  us* qh  = (us*)(ws + 0 * MB);
  us* ql  = (us*)(ws + 16 * MB);
  us* kh  = (us*)(ws + 32 * MB);
  us* kl  = (us*)(ws + 48 * MB);
  us* vtmp_h = (us*)(ws + 64 * MB);
  us* vtmp_l = (us*)(ws + 80 * MB);
  us* wth = (us*)(ws + 96 * MB);
  us* wtl = (us*)(ws + 102 * MB);
  us* xh  = (us*)(ws + 108 * MB);
  us* xl  = (us*)(ws + 124 * MB);
  us* vth = (us*)(ws + 96 * MB);
  us* vtl = (us*)(ws + 112 * MB);

  wt_prep<<<dim3(16, 16, 3), 256, 0, stream>>>(Wq, Wk, Wv, wth, wtl);
  xsplit<<<dim3(4096), 256, 0, stream>>>(x, xh, xl);
  qkv_gemm<<<dim3(64, 8, 3), 256, 0, stream>>>(xh, xl, wth, wtl, bq, bk, bv,
                                               qh, ql, kh, kl, vtmp_h, vtmp_l);
  vtrans<<<dim3(16, 32, 8), 256, 0, stream>>>(vtmp_h, vtmp_l, vth, vtl);

  if (ws_size >= 236 * MB) {
    _Float16* scores = (_Float16*)(ws + 140 * MB);
    us* ph  = (us*)(ws + 172 * MB);
    us* plo = (us*)(ws + 204 * MB);
    s2_gemm<<<dim3(16, 16, 4), 256, 0, stream>>>(qh, ql, kh, kl, scores);
    softmax_k<<<dim3(B_ * S_), 256, 0, stream>>>(scores, ph, plo);
    s3_gemm<<<dim3(16, 8, 4), 256, 0, stream>>>(ph, plo, vth, vtl, out);
  } else {
    // compact fallback: per-batch, scores/P reuse dead vtmp region [64,96)
    _Float16* scores = (_Float16*)(ws + 64 * MB);
    us* ph  = (us*)(ws + 73 * MB);
    us* plo = (us*)(ws + 82 * MB);
    for (int b = 0; b < B_; ++b) {
      size_t o  = (size_t)b * S_ * D_;
      size_t ot = (size_t)b * D_ * S_;
      s2_gemm<<<dim3(16, 16, 1), 256, 0, stream>>>(qh + o, ql + o, kh + o, kl + o, scores);
      softmax_k<<<dim3(S_), 256, 0, stream>>>(scores, ph, plo);
      s3_gemm<<<dim3(16, 8, 1), 256, 0, stream>>>(ph, plo, vth + ot, vtl + ot, out + o);
    }
  }
}

// Round 3
// 200.697 us; speedup vs baseline: 3.6346x; 2.0377x over previous
//
#include <hip/hip_runtime.h>
#include <hip/hip_bf16.h>
#include <stdint.h>

// SelfAttention: x[4,2048,1024] fp32; q=xWq+bq, k=xWk+bk, v=xWv+bv;
// out = softmax(q k^T / 32) v.
// R3: plain 1-term bf16 MFMA everywhere (error budget: flat softmax kills
// rounding noise; predicted absmax ~5e-4-1e-3 < 1.78e-3 threshold).
// Raw MFMA work 360 -> 120 GF. Structure stays the proven m97 shape.

typedef short bf16x8 __attribute__((ext_vector_type(8)));
typedef float f32x4 __attribute__((ext_vector_type(4)));
typedef unsigned short us4 __attribute__((ext_vector_type(4)));
typedef _Float16 h4 __attribute__((ext_vector_type(4)));
typedef unsigned short us;

#define B_ 4
#define S_ 2048
#define D_ 1024

__device__ __forceinline__ us f2bf(float f) {
  unsigned int u = __float_as_uint(f);
  unsigned int r = (u + 0x7fffu + ((u >> 16) & 1u)) >> 16;  // RNE
  return (us)r;
}

// async global->LDS, 16B per lane. lds addr wave-uniform; global per-lane.
__device__ __forceinline__ void gl2lds16(void* lds, const void* g) {
  __builtin_amdgcn_global_load_lds(
      (const __attribute__((address_space(1))) unsigned int*)(uintptr_t)g,
      (__attribute__((address_space(3))) unsigned int*)(uintptr_t)lds,
      16, 0, 0);
}

// 128-row x 64-byte tile (global row stride = stride_bytes) -> linear LDS [128][64B].
__device__ __forceinline__ void stage128x64(void* lds, const void* g, int stride_bytes,
                                            int wave, int lane) {
  const char* gc = (const char*)g;
  char* lc = (char*)lds;
#pragma unroll
  for (int i = 0; i < 2; ++i) {
    int rbase = wave * 32 + i * 16;
    int row = rbase + (lane >> 2);
    gl2lds16(lc + rbase * 64,
             gc + (size_t)row * stride_bytes + (size_t)(lane & 3) * 16);
  }
}

// One K-step (BK=32): 4x4 fragments of 16x16x32 per wave (m97 shape).
// LDS: [128 rows][32 k] bf16 linear.
__device__ __forceinline__ void mfma_block1(const us* a, const us* b,
                                            f32x4 acc[4][4], int lane, int wm, int wn) {
  int r15 = lane & 15, kg = lane >> 4;
  bf16x8 A[4], B[4];
#pragma unroll
  for (int f = 0; f < 4; ++f) {
    A[f] = *(const bf16x8*)(a + (wm * 64 + f * 16 + r15) * 32 + kg * 8);
    B[f] = *(const bf16x8*)(b + (wn * 64 + f * 16 + r15) * 32 + kg * 8);
  }
#pragma unroll
  for (int i = 0; i < 4; ++i)
#pragma unroll
    for (int j = 0; j < 4; ++j)
      acc[i][j] = __builtin_amdgcn_mfma_f32_16x16x32_bf16(A[i], B[j], acc[i][j], 0, 0, 0);
}

// ---------------- W [k][n] fp32 -> Wt bf16 [n][k] ----------------
__global__ __launch_bounds__(256) void wt_prep(const float* __restrict__ Wq,
                                               const float* __restrict__ Wk,
                                               const float* __restrict__ Wv,
                                               us* __restrict__ wtb) {
  __shared__ us hs[64][65];
  int mat = blockIdx.z;
  const float* W = (mat == 0) ? Wq : (mat == 1) ? Wk : Wv;
  int n0 = blockIdx.x * 64, k0 = blockIdx.y * 64;
  int tid = threadIdx.x;
#pragma unroll
  for (int i = 0; i < 16; ++i) {
    int idx = tid + i * 256;
    int r = idx >> 6, c = idx & 63;  // r: k, c: n
    hs[r][c] = f2bf(W[(size_t)(k0 + r) * D_ + (n0 + c)]);
  }
  __syncthreads();
  us* o = wtb + ((size_t)mat << 20);
#pragma unroll
  for (int i = 0; i < 16; ++i) {
    int idx = tid + i * 256;
    int r = idx >> 6, c = idx & 63;  // r: n, c: k
    o[(size_t)(n0 + r) * D_ + (k0 + c)] = hs[c][r];
  }
}

// ---------------- x fp32 -> xb bf16 (same [m][k] layout) ----------------
__global__ __launch_bounds__(256) void xcast(const float* __restrict__ x,
                                             us* __restrict__ xb) {
  size_t i = ((size_t)blockIdx.x * 256 + threadIdx.x) * 8;
  float4 f0 = *(const float4*)(x + i);
  float4 f1 = *(const float4*)(x + i + 4);
  float vals[8] = {f0.x, f0.y, f0.z, f0.w, f1.x, f1.y, f1.z, f1.w};
  union { bf16x8 v; us s_[8]; } H;
#pragma unroll
  for (int e = 0; e < 8; ++e) H.s_[e] = f2bf(vals[e]);
  *(bf16x8*)(xb + i) = H.v;
}

// ---------------- QKV projection: C[m][n] = x[m][:] . Wt[n][:] + bias[n] ----------------
__global__ __launch_bounds__(256) void qkv_gemm(
    const us* __restrict__ xb, const us* __restrict__ wtb,
    const float* __restrict__ bq, const float* __restrict__ bk, const float* __restrict__ bv,
    us* __restrict__ qb, us* __restrict__ kb, us* __restrict__ vb) {
  __shared__ __align__(16) us ah[128 * 32];
  __shared__ __align__(16) us bh[128 * 32];
  int tid = threadIdx.x, lane = tid & 63, wave = tid >> 6;
  int wm = wave >> 1, wn = wave & 1;
  int m0 = blockIdx.x * 128, n0 = blockIdx.y * 128;
  int mat = blockIdx.z;
  const us* wb = wtb + ((size_t)mat << 20);
  const float* bias = (mat == 0) ? bq : (mat == 1) ? bk : bv;
  us* ob = (mat == 0) ? qb : (mat == 1) ? kb : vb;

  f32x4 acc[4][4] = {};
  for (int kk = 0; kk < D_; kk += 32) {
    stage128x64(ah, xb + (size_t)m0 * D_ + kk, D_ * 2, wave, lane);
    stage128x64(bh, wb + (size_t)n0 * D_ + kk, D_ * 2, wave, lane);
    __syncthreads();
    mfma_block1(ah, bh, acc, lane, wm, wn);
    __syncthreads();
  }
#pragma unroll
  for (int fi = 0; fi < 4; ++fi)
#pragma unroll
    for (int fj = 0; fj < 4; ++fj) {
      int col = n0 + wn * 64 + fj * 16 + (lane & 15);
      float bb = bias[col];
#pragma unroll
      for (int r = 0; r < 4; ++r) {
        int row = m0 + wm * 64 + fi * 16 + (lane >> 4) * 4 + r;
        ob[(size_t)row * D_ + col] = f2bf(acc[fi][fj][r] + bb);
      }
    }
}

// ---------------- v [b][t][d] -> vT [b][d][t] ----------------
__global__ __launch_bounds__(256) void vtrans(const us* __restrict__ vin,
                                              us* __restrict__ vout) {
  int b = blockIdx.z;
  const us* vi = vin + (size_t)b * S_ * D_;
  us* vo = vout + (size_t)b * D_ * S_;
  int d0 = blockIdx.x * 64, t0 = blockIdx.y * 64;
  __shared__ us ts[64][72];
  int tid = threadIdx.x;
#pragma unroll
  for (int i = 0; i < 16; ++i) {
    int idx = tid + i * 256;
    int r = idx >> 6, c = idx & 63;  // r: t, c: d
    ts[r][c] = vi[(size_t)(t0 + r) * D_ + d0 + c];
  }
  __syncthreads();
#pragma unroll
  for (int i = 0; i < 16; ++i) {
    int idx = tid + i * 256;
    int r = idx >> 6, c = idx & 63;  // r: d, c: t
    vo[(size_t)(d0 + r) * S_ + t0 + c] = ts[c][r];
  }
}

// ---------------- scores = q k^T / 32, fp16 out. z = batch ----------------
__global__ __launch_bounds__(256) void s2_gemm(const us* __restrict__ qb,
                                               const us* __restrict__ kb,
                                               _Float16* __restrict__ scores) {
  __shared__ __align__(16) us ah[128 * 32];
  __shared__ __align__(16) us bh[128 * 32];
  int tid = threadIdx.x, lane = tid & 63, wave = tid >> 6;
  int wm = wave >> 1, wn = wave & 1;
  int m0 = blockIdx.x * 128, n0 = blockIdx.y * 128;
  size_t b = blockIdx.z;
  const us* q_b = qb + b * (size_t)(S_ * D_);
  const us* k_b = kb + b * (size_t)(S_ * D_);
  _Float16* sc = scores + b * (size_t)(S_ * S_);
  f32x4 acc[4][4] = {};
  for (int kk = 0; kk < D_; kk += 32) {
    stage128x64(ah, q_b + (size_t)m0 * D_ + kk, D_ * 2, wave, lane);
    stage128x64(bh, k_b + (size_t)n0 * D_ + kk, D_ * 2, wave, lane);
    __syncthreads();
    mfma_block1(ah, bh, acc, lane, wm, wn);
    __syncthreads();
  }
#pragma unroll
  for (int fi = 0; fi < 4; ++fi)
#pragma unroll
    for (int fj = 0; fj < 4; ++fj) {
      int col = n0 + wn * 64 + fj * 16 + (lane & 15);
#pragma unroll
      for (int r = 0; r < 4; ++r) {
        int row = m0 + wm * 64 + fi * 16 + (lane >> 4) * 4 + r;
        sc[(size_t)row * S_ + col] = (_Float16)(acc[fi][fj][r] * 0.03125f);
      }
    }
}

// ---------------- row softmax: fp16 scores -> P bf16 ----------------
__global__ __launch_bounds__(256) void softmax_k(const _Float16* __restrict__ scores,
                                                 us* __restrict__ pb) {
  int row = blockIdx.x, tid = threadIdx.x, lane = tid & 63, wave = tid >> 6;
  const _Float16* s = scores + (size_t)row * S_;
  h4 a4 = ((const h4*)s)[tid];
  h4 b4 = ((const h4*)s)[256 + tid];
  float a[8] = {(float)a4.x, (float)a4.y, (float)a4.z, (float)a4.w,
                (float)b4.x, (float)b4.y, (float)b4.z, (float)b4.w};
  float m = a[0];
#pragma unroll
  for (int e = 1; e < 8; ++e) m = fmaxf(m, a[e]);
#pragma unroll
  for (int o = 32; o; o >>= 1) m = fmaxf(m, __shfl_xor(m, o));
  __shared__ float red[4];
  if (lane == 0) red[wave] = m;
  __syncthreads();
  m = fmaxf(fmaxf(red[0], red[1]), fmaxf(red[2], red[3]));
  float p[8];
  float sum = 0.f;
#pragma unroll
  for (int e = 0; e < 8; ++e) { p[e] = expf(a[e] - m); sum += p[e]; }
#pragma unroll
  for (int o = 32; o; o >>= 1) sum += __shfl_xor(sum, o);
  __syncthreads();  // all reads of red done before reuse
  if (lane == 0) red[wave] = sum;
  __syncthreads();
  float inv = 1.0f / (red[0] + red[1] + red[2] + red[3]);
  us h[8];
#pragma unroll
  for (int e = 0; e < 8; ++e) h[e] = f2bf(p[e] * inv);
  size_t base = (size_t)row * S_;
  *(us4*)(pb + base + tid * 4) = (us4){h[0], h[1], h[2], h[3]};
  *(us4*)(pb + base + 1024 + tid * 4) = (us4){h[4], h[5], h[6], h[7]};
}

// ---------------- out = P vT, K = 2048. z = batch ----------------
__global__ __launch_bounds__(256) void s3_gemm(const us* __restrict__ pb,
                                               const us* __restrict__ vtb,
                                               float* __restrict__ out) {
  __shared__ __align__(16) us ah[128 * 32];
  __shared__ __align__(16) us bh[128 * 32];
  int tid = threadIdx.x, lane = tid & 63, wave = tid >> 6;
  int wm = wave >> 1, wn = wave & 1;
  int m0 = blockIdx.x * 128, n0 = blockIdx.y * 128;
  size_t b = blockIdx.z;
  const us* p_b = pb + b * (size_t)(S_ * S_);
  const us* v_b = vtb + b * (size_t)(D_ * S_);
  float* out_b = out + b * (size_t)(S_ * D_);
  f32x4 acc[4][4] = {};
  for (int kk = 0; kk < S_; kk += 32) {
    stage128x64(ah, p_b + (size_t)m0 * S_ + kk, S_ * 2, wave, lane);
    stage128x64(bh, v_b + (size_t)n0 * S_ + kk, S_ * 2, wave, lane);
    __syncthreads();
    mfma_block1(ah, bh, acc, lane, wm, wn);
    __syncthreads();
  }
#pragma unroll
  for (int fi = 0; fi < 4; ++fi)
#pragma unroll
    for (int fj = 0; fj < 4; ++fj) {
      int col = n0 + wn * 64 + fj * 16 + (lane & 15);
#pragma unroll
      for (int r = 0; r < 4; ++r) {
        int row = m0 + wm * 64 + fi * 16 + (lane >> 4) * 4 + r;
        out_b[(size_t)row * D_ + col] = acc[fi][fj][r];
      }
    }
}

extern "C" void kernel_launch(void* const* d_in, const int* in_sizes, int n_in,
                              void* d_out, int out_size, void* d_ws, size_t ws_size,
                              hipStream_t stream) {
  const float* x  = (const float*)d_in[0];
  const float* Wq = (const float*)d_in[1];
  const float* bq = (const float*)d_in[2];
  const float* Wk = (const float*)d_in[3];
  const float* bk = (const float*)d_in[4];
  const float* Wv = (const float*)d_in[5];
  const float* bv = (const float*)d_in[6];
  float* out = (float*)d_out;
  char* ws = (char*)d_ws;
  const size_t MB = 1024 * 1024;
  // Layout (134 MiB total, under the 140 MiB proven in R1):
  //  [0,16)    qb        [16,32)  kb        [32,48)  vtmp
  //  [48,54)   wtb       [54,70)  xb        [70,86)  vtb
  //  [86,118)  scores fp16 (32MB) [118,134) pb
  us* qb   = (us*)(ws + 0 * MB);
  us* kb   = (us*)(ws + 16 * MB);
  us* vtmp = (us*)(ws + 32 * MB);
  us* wtb  = (us*)(ws + 48 * MB);
  us* xb   = (us*)(ws + 54 * MB);
  us* vtb  = (us*)(ws + 70 * MB);
  _Float16* scores = (_Float16*)(ws + 86 * MB);
  us* pb   = (us*)(ws + 118 * MB);

  wt_prep<<<dim3(16, 16, 3), 256, 0, stream>>>(Wq, Wk, Wv, wtb);
  xcast<<<dim3(4096), 256, 0, stream>>>(x, xb);
  qkv_gemm<<<dim3(64, 8, 3), 256, 0, stream>>>(xb, wtb, bq, bk, bv, qb, kb, vtmp);
  vtrans<<<dim3(16, 32, 4), 256, 0, stream>>>(vtmp, vtb);
  s2_gemm<<<dim3(16, 16, 4), 256, 0, stream>>>(qb, kb, scores);
  softmax_k<<<dim3(B_ * S_), 256, 0, stream>>>(scores, pb);
  s3_gemm<<<dim3(16, 8, 4), 256, 0, stream>>>(pb, vtb, out);
}

// Round 4
// 180.893 us; speedup vs baseline: 4.0325x; 1.1095x over previous
//
#include <hip/hip_runtime.h>
#include <hip/hip_bf16.h>
#include <stdint.h>

// SelfAttention: x[4,2048,1024] fp32; q=xWq+bq, k=xWk+bk, v=xWv+bv;
// out = softmax(q k^T / 32) v.
// R4: deep-pipelined GEMM (128x256 tile, BK=64, 8 waves, LDS dbuf 96KB,
// T2 XOR-swizzle + counted vmcnt (never 0 mid-loop) + setprio).
// All three GEMMs share one template; qkv folds the 3 mats into N=3072.

typedef short bf16x8 __attribute__((ext_vector_type(8)));
typedef float f32x4 __attribute__((ext_vector_type(4)));
typedef unsigned short us4 __attribute__((ext_vector_type(4)));
typedef _Float16 h4 __attribute__((ext_vector_type(4)));
typedef unsigned short us;

#define B_ 4
#define S_ 2048
#define D_ 1024

__device__ __forceinline__ us f2bf(float f) {
  unsigned int u = __float_as_uint(f);
  unsigned int r = (u + 0x7fffu + ((u >> 16) & 1u)) >> 16;  // RNE
  return (us)r;
}

// async global->LDS, 16B per lane. lds addr wave-uniform; global per-lane.
__device__ __forceinline__ void gl2lds16(void* lds, const void* g) {
  __builtin_amdgcn_global_load_lds(
      (const __attribute__((address_space(1))) unsigned int*)(uintptr_t)g,
      (__attribute__((address_space(3))) unsigned int*)(uintptr_t)lds,
      16, 0, 0);
}

__device__ __forceinline__ void wait_vm6() {
  asm volatile("s_waitcnt vmcnt(6)" ::: "memory");
}
__device__ __forceinline__ void wait_vm0() {
  asm volatile("s_waitcnt vmcnt(0)" ::: "memory");
}
__device__ __forceinline__ void wait_lgkm0() {
  asm volatile("s_waitcnt lgkmcnt(0)" ::: "memory");
}
__device__ __forceinline__ void sbar() {
  __builtin_amdgcn_sched_barrier(0);
  __builtin_amdgcn_s_barrier();
  __builtin_amdgcn_sched_barrier(0);
}

// ---------------- 8-wave deep-pipelined GEMM core ----------------
// Tile BM=128 x BN=256, BK=64. LDS buffer: A[128][64] + B[256][64] bf16,
// XOR-swizzled: LDS[row][kb ^ ((row&7)<<4)] = G[row][kb] (byte offsets).
// Stage: linear gl2lds dest + pre-swizzled global source (both-sides involution).
// 6 gl2lds/thread per K-tile (A 2 rounds, B 4 rounds of 64 rows x 128B).

__device__ __forceinline__ void stage_tile(us* buf, const us* gA, size_t sA,
                                           const us* gB, size_t sB,
                                           int wave, int lane) {
  char* lA = (char*)buf;
  char* lB = (char*)(buf + 8192);
  int slot = ((lane & 7) ^ (lane >> 3)) << 4;   // pre-swizzled source slot
  int rw = wave * 8 + (lane >> 3);              // row&7 == lane>>3
  const char* a = (const char*)gA;
  const char* b = (const char*)gB;
#pragma unroll
  for (int r = 0; r < 2; ++r)
    gl2lds16(lA + r * 8192 + wave * 1024, a + (size_t)(r * 64 + rw) * sA + slot);
#pragma unroll
  for (int r = 0; r < 4; ++r)
    gl2lds16(lB + r * 8192 + wave * 1024, b + (size_t)(r * 64 + rw) * sB + slot);
}

// One K-tile (64): read 16 swizzled b128 frags, 2x16 MFMA clusters; restage
// this buffer with tile i+2 after the mid-tile barrier (all reads complete).
template<bool DOSTAGE>
__device__ __forceinline__ void ktile(const us* buf, f32x4 acc[4][4],
                                      int lane, int wm, int wn, int wave,
                                      us* stagebuf, const us* sgA, size_t sA,
                                      const us* sgB, size_t sB) {
  const char* lA = (const char*)buf;
  const char* lB = (const char*)(buf + 8192);
  int x0 = (((lane >> 4) ^ (lane & 7)) << 4);   // swizzled k-offset, ks=0
  int ar = (wm * 64 + (lane & 15)) * 128;
  int br = (wn * 64 + (lane & 15)) * 128;
  bf16x8 Af[8], Bf[8];
#pragma unroll
  for (int f = 0; f < 4; ++f) {
    Af[f * 2]     = *(const bf16x8*)(lA + ar + f * 2048 + x0);
    Af[f * 2 + 1] = *(const bf16x8*)(lA + ar + f * 2048 + (x0 ^ 64));
  }
#pragma unroll
  for (int f = 0; f < 4; ++f) {
    Bf[f * 2]     = *(const bf16x8*)(lB + br + f * 2048 + x0);
    Bf[f * 2 + 1] = *(const bf16x8*)(lB + br + f * 2048 + (x0 ^ 64));
  }
  __builtin_amdgcn_s_setprio(1);
#pragma unroll
  for (int fn = 0; fn < 2; ++fn)
#pragma unroll
    for (int fm = 0; fm < 4; ++fm) {
      acc[fm][fn] = __builtin_amdgcn_mfma_f32_16x16x32_bf16(Af[fm*2],   Bf[fn*2],   acc[fm][fn], 0, 0, 0);
      acc[fm][fn] = __builtin_amdgcn_mfma_f32_16x16x32_bf16(Af[fm*2+1], Bf[fn*2+1], acc[fm][fn], 0, 0, 0);
    }
  __builtin_amdgcn_s_setprio(0);
  wait_lgkm0();          // all 16 reads of this buffer complete (in regs)
  sbar();                // ... for every wave -> safe to restage this buffer
  if (DOSTAGE) stage_tile(stagebuf, sgA, sA, sgB, sB, wave, lane);
  __builtin_amdgcn_sched_barrier(0);
  __builtin_amdgcn_s_setprio(1);
#pragma unroll
  for (int fn = 2; fn < 4; ++fn)
#pragma unroll
    for (int fm = 0; fm < 4; ++fm) {
      acc[fm][fn] = __builtin_amdgcn_mfma_f32_16x16x32_bf16(Af[fm*2],   Bf[fn*2],   acc[fm][fn], 0, 0, 0);
      acc[fm][fn] = __builtin_amdgcn_mfma_f32_16x16x32_bf16(Af[fm*2+1], Bf[fn*2+1], acc[fm][fn], 0, 0, 0);
    }
  __builtin_amdgcn_s_setprio(0);
}

// EPI: 0 = qkv (bf16 out + bias, mats folded in N), 1 = s2 (fp16, *1/32), 2 = s3 (f32)
template<int EPI>
__global__ __launch_bounds__(512, 2) void gemm8(
    const us* __restrict__ Aall, const us* __restrict__ Ball,
    size_t aBatch, size_t bBatch, int strideAe, int strideBe, int nt,
    const float* __restrict__ bq, const float* __restrict__ bk,
    const float* __restrict__ bv, void* __restrict__ outp) {
  __shared__ __align__(16) us lds[2][24576];   // 96 KiB
  int tid = threadIdx.x, lane = tid & 63, wave = tid >> 6;
  int wm = wave >> 2, wn = wave & 3;
  int m0 = blockIdx.x * 128, n0 = blockIdx.y * 256;
  size_t bz = blockIdx.z;
  const us* gA = Aall + bz * aBatch + (size_t)m0 * strideAe;
  const us* gB = Ball + bz * bBatch + (size_t)n0 * strideBe;
  size_t sA = (size_t)strideAe * 2, sB = (size_t)strideBe * 2;

  // prologue: 2 tiles in flight
  stage_tile(lds[0], gA, sA, gB, sB, wave, lane);
  stage_tile(lds[1], gA + 64, sA, gB + 64, sB, wave, lane);

  f32x4 acc[4][4] = {};
  for (int i = 0; i < nt - 1; ++i) {
    wait_vm6();          // drain tile i's 6 loads; keep tile i+1's in flight
    sbar();
    if (i + 2 < nt)
      ktile<true>(lds[i & 1], acc, lane, wm, wn, wave,
                  lds[i & 1], gA + (size_t)(i + 2) * 64, sA,
                  gB + (size_t)(i + 2) * 64, sB);
    else
      ktile<false>(lds[i & 1], acc, lane, wm, wn, wave,
                   nullptr, nullptr, 0, nullptr, 0);
  }
  wait_vm0();            // final tile: nothing newer in flight
  sbar();
  ktile<false>(lds[(nt - 1) & 1], acc, lane, wm, wn, wave,
               nullptr, nullptr, 0, nullptr, 0);

#pragma unroll
  for (int fm = 0; fm < 4; ++fm)
#pragma unroll
    for (int fn = 0; fn < 4; ++fn) {
      int col = n0 + wn * 64 + fn * 16 + (lane & 15);
      int row0 = m0 + wm * 64 + fm * 16 + ((lane >> 4) << 2);
      if constexpr (EPI == 0) {
        int mat = col >> 10;
        const float* bp = (mat == 0) ? bq : (mat == 1) ? bk : bv;
        float bb = bp[col & 1023];
        us* ob = (us*)outp + ((size_t)mat << 23);
#pragma unroll
        for (int r = 0; r < 4; ++r)
          ob[(size_t)(row0 + r) * D_ + (col & 1023)] = f2bf(acc[fm][fn][r] + bb);
      } else if constexpr (EPI == 1) {
        _Float16* sc = (_Float16*)outp + bz * (size_t)(S_ * S_);
#pragma unroll
        for (int r = 0; r < 4; ++r)
          sc[(size_t)(row0 + r) * S_ + col] = (_Float16)(acc[fm][fn][r] * 0.03125f);
      } else {
        float* ob = (float*)outp + bz * (size_t)(S_ * D_);
#pragma unroll
        for (int r = 0; r < 4; ++r)
          ob[(size_t)(row0 + r) * D_ + col] = acc[fm][fn][r];
      }
    }
}

// ---------------- W [k][n] fp32 -> Wt bf16 [n][k] (n = mat*1024 + col) ----------------
__global__ __launch_bounds__(256) void wt_prep(const float* __restrict__ Wq,
                                               const float* __restrict__ Wk,
                                               const float* __restrict__ Wv,
                                               us* __restrict__ wtb) {
  __shared__ us hs[64][65];
  int mat = blockIdx.z;
  const float* W = (mat == 0) ? Wq : (mat == 1) ? Wk : Wv;
  int n0 = blockIdx.x * 64, k0 = blockIdx.y * 64;
  int tid = threadIdx.x;
#pragma unroll
  for (int i = 0; i < 16; ++i) {
    int idx = tid + i * 256;
    int r = idx >> 6, c = idx & 63;  // r: k, c: n
    hs[r][c] = f2bf(W[(size_t)(k0 + r) * D_ + (n0 + c)]);
  }
  __syncthreads();
  us* o = wtb + ((size_t)mat << 20);
#pragma unroll
  for (int i = 0; i < 16; ++i) {
    int idx = tid + i * 256;
    int r = idx >> 6, c = idx & 63;  // r: n, c: k
    o[(size_t)(n0 + r) * D_ + (k0 + c)] = hs[c][r];
  }
}

// ---------------- x fp32 -> xb bf16 (same [m][k] layout) ----------------
__global__ __launch_bounds__(256) void xcast(const float* __restrict__ x,
                                             us* __restrict__ xb) {
  size_t i = ((size_t)blockIdx.x * 256 + threadIdx.x) * 8;
  float4 f0 = *(const float4*)(x + i);
  float4 f1 = *(const float4*)(x + i + 4);
  float vals[8] = {f0.x, f0.y, f0.z, f0.w, f1.x, f1.y, f1.z, f1.w};
  union { bf16x8 v; us s_[8]; } H;
#pragma unroll
  for (int e = 0; e < 8; ++e) H.s_[e] = f2bf(vals[e]);
  *(bf16x8*)(xb + i) = H.v;
}

// ---------------- v [b][t][d] -> vT [b][d][t] ----------------
__global__ __launch_bounds__(256) void vtrans(const us* __restrict__ vin,
                                              us* __restrict__ vout) {
  int b = blockIdx.z;
  const us* vi = vin + (size_t)b * S_ * D_;
  us* vo = vout + (size_t)b * D_ * S_;
  int d0 = blockIdx.x * 64, t0 = blockIdx.y * 64;
  __shared__ us ts[64][72];
  int tid = threadIdx.x;
#pragma unroll
  for (int i = 0; i < 16; ++i) {
    int idx = tid + i * 256;
    int r = idx >> 6, c = idx & 63;  // r: t, c: d
    ts[r][c] = vi[(size_t)(t0 + r) * D_ + d0 + c];
  }
  __syncthreads();
#pragma unroll
  for (int i = 0; i < 16; ++i) {
    int idx = tid + i * 256;
    int r = idx >> 6, c = idx & 63;  // r: d, c: t
    vo[(size_t)(d0 + r) * S_ + t0 + c] = ts[c][r];
  }
}

// ---------------- row softmax: fp16 scores -> P bf16 ----------------
__global__ __launch_bounds__(256) void softmax_k(const _Float16* __restrict__ scores,
                                                 us* __restrict__ pb) {
  int row = blockIdx.x, tid = threadIdx.x, lane = tid & 63, wave = tid >> 6;
  const _Float16* s = scores + (size_t)row * S_;
  h4 a4 = ((const h4*)s)[tid];
  h4 b4 = ((const h4*)s)[256 + tid];
  float a[8] = {(float)a4.x, (float)a4.y, (float)a4.z, (float)a4.w,
                (float)b4.x, (float)b4.y, (float)b4.z, (float)b4.w};
  float m = a[0];
#pragma unroll
  for (int e = 1; e < 8; ++e) m = fmaxf(m, a[e]);
#pragma unroll
  for (int o = 32; o; o >>= 1) m = fmaxf(m, __shfl_xor(m, o));
  __shared__ float red[4];
  if (lane == 0) red[wave] = m;
  __syncthreads();
  m = fmaxf(fmaxf(red[0], red[1]), fmaxf(red[2], red[3]));
  float p[8];
  float sum = 0.f;
#pragma unroll
  for (int e = 0; e < 8; ++e) { p[e] = expf(a[e] - m); sum += p[e]; }
#pragma unroll
  for (int o = 32; o; o >>= 1) sum += __shfl_xor(sum, o);
  __syncthreads();  // all reads of red done before reuse
  if (lane == 0) red[wave] = sum;
  __syncthreads();
  float inv = 1.0f / (red[0] + red[1] + red[2] + red[3]);
  us h[8];
#pragma unroll
  for (int e = 0; e < 8; ++e) h[e] = f2bf(p[e] * inv);
  size_t base = (size_t)row * S_;
  *(us4*)(pb + base + tid * 4) = (us4){h[0], h[1], h[2], h[3]};
  *(us4*)(pb + base + 1024 + tid * 4) = (us4){h[4], h[5], h[6], h[7]};
}

extern "C" void kernel_launch(void* const* d_in, const int* in_sizes, int n_in,
                              void* d_out, int out_size, void* d_ws, size_t ws_size,
                              hipStream_t stream) {
  const float* x  = (const float*)d_in[0];
  const float* Wq = (const float*)d_in[1];
  const float* bq = (const float*)d_in[2];
  const float* Wk = (const float*)d_in[3];
  const float* bk = (const float*)d_in[4];
  const float* Wv = (const float*)d_in[5];
  const float* bv = (const float*)d_in[6];
  float* out = (float*)d_out;
  char* ws = (char*)d_ws;
  const size_t MB = 1024 * 1024;
  // Layout (134 MiB total; qb/kb/vtmp contiguous = qkv output base):
  //  [0,16)  qb   [16,32) kb   [32,48) vtmp
  //  [48,54) wtb  [54,70) xb   [70,86) vtb
  //  [86,118) scores fp16      [118,134) pb
  us* qb   = (us*)(ws + 0 * MB);
  us* kb   = (us*)(ws + 16 * MB);
  us* wtb  = (us*)(ws + 48 * MB);
  us* xb   = (us*)(ws + 54 * MB);
  us* vtmp = (us*)(ws + 32 * MB);
  us* vtb  = (us*)(ws + 70 * MB);
  _Float16* scores = (_Float16*)(ws + 86 * MB);
  us* pb   = (us*)(ws + 118 * MB);

  wt_prep<<<dim3(16, 16, 3), 256, 0, stream>>>(Wq, Wk, Wv, wtb);
  xcast<<<dim3(4096), 256, 0, stream>>>(x, xb);
  // qkv: M=8192 x N=3072 (3 mats) x K=1024
  gemm8<0><<<dim3(64, 12, 1), 512, 0, stream>>>(xb, wtb, 0, 0, D_, D_, 16,
                                                bq, bk, bv, qb);
  vtrans<<<dim3(16, 32, 4), 256, 0, stream>>>(vtmp, vtb);
  // s2: per batch M=2048 x N=2048 x K=1024
  gemm8<1><<<dim3(16, 8, 4), 512, 0, stream>>>(qb, kb,
                                               (size_t)S_ * D_, (size_t)S_ * D_,
                                               D_, D_, 16,
                                               nullptr, nullptr, nullptr, scores);
  softmax_k<<<dim3(B_ * S_), 256, 0, stream>>>(scores, pb);
  // s3: per batch M=2048 x N=1024 x K=2048
  gemm8<2><<<dim3(16, 4, 4), 512, 0, stream>>>(pb, vtb,
                                               (size_t)S_ * S_, (size_t)D_ * S_,
                                               S_, S_, 32,
                                               nullptr, nullptr, nullptr, out);
}

// Round 5
// 158.103 us; speedup vs baseline: 4.6137x; 1.1441x over previous
//
#include <hip/hip_runtime.h>
#include <hip/hip_bf16.h>
#include <stdint.h>

// SelfAttention: x[4,2048,1024] fp32; q=xWq+bq, k=xWk+bk, v=xWv+bv;
// out = softmax(q k^T / 32) v.
// R5: 3-buffer LDS rotation (144KB) -> ONE barrier per K-tile; 2 micro-phases
// (k-slice) per tile with stage-issue-early; counted vmcnt(6); T2 swizzle
// (verified: 0 bank conflicts); setprio around MFMA clusters.
// s3 re-tiled 256x128 -> 256 blocks (1 exact round).

typedef short bf16x8 __attribute__((ext_vector_type(8)));
typedef float f32x4 __attribute__((ext_vector_type(4)));
typedef unsigned short us4 __attribute__((ext_vector_type(4)));
typedef _Float16 h4 __attribute__((ext_vector_type(4)));
typedef unsigned short us;

#define B_ 4
#define S_ 2048
#define D_ 1024

__device__ __forceinline__ us f2bf(float f) {
  unsigned int u = __float_as_uint(f);
  unsigned int r = (u + 0x7fffu + ((u >> 16) & 1u)) >> 16;  // RNE
  return (us)r;
}

// async global->LDS, 16B per lane. lds addr wave-uniform; global per-lane.
__device__ __forceinline__ void gl2lds16(void* lds, const void* g) {
  __builtin_amdgcn_global_load_lds(
      (const __attribute__((address_space(1))) unsigned int*)(uintptr_t)g,
      (__attribute__((address_space(3))) unsigned int*)(uintptr_t)lds,
      16, 0, 0);
}

__device__ __forceinline__ void wait_vm6() {
  asm volatile("s_waitcnt vmcnt(6)" ::: "memory");
}
__device__ __forceinline__ void wait_vm0() {
  asm volatile("s_waitcnt vmcnt(0)" ::: "memory");
}
__device__ __forceinline__ void sbar() {
  __builtin_amdgcn_sched_barrier(0);
  __builtin_amdgcn_s_barrier();
  __builtin_amdgcn_sched_barrier(0);
}

// Stage rounds [R0,R1) of a 384-row x 128B K-tile (rows 0..BM-1 = A, rest = B).
// Round r covers rows r*64..r*64+63; 1 gl2lds per thread per round.
// LDS dest linear; global source pre-swizzled (involution, row&7 = lane>>3).
template<int BM, int R0, int R1>
__device__ __forceinline__ void stageR(us* buf, const us* gA, size_t sA,
                                       const us* gB, size_t sB,
                                       int wave, int lane) {
  int slot = ((lane & 7) ^ (lane >> 3)) << 4;
  char* l = (char*)buf;
#pragma unroll
  for (int r = R0; r < R1; ++r) {
    int row = r * 64 + wave * 8 + (lane >> 3);
    const char* src;
    if (r * 64 < BM)  // compile-time per unrolled r (BM multiple of 64)
      src = (const char*)gA + (size_t)row * sA + slot;
    else
      src = (const char*)gB + (size_t)(row - BM) * sB + slot;
    gl2lds16(l + r * 8192 + wave * 1024, src);
  }
}

// EPI: 0 = qkv (bf16 out + bias, 3 mats folded in N), 1 = s2 (fp16, *1/32), 2 = s3 (f32)
template<int EPI, int BM, int BN, int WMS, int WNS>
__global__ __launch_bounds__(512, 2) void gemm8p(
    const us* __restrict__ Aall, const us* __restrict__ Ball,
    size_t aBatch, size_t bBatch, int sAe, int sBe, int nt,
    const float* __restrict__ bq, const float* __restrict__ bk,
    const float* __restrict__ bv, void* __restrict__ outp) {
  __shared__ __align__(16) us lds[3][(BM + BN) * 64];   // 3 x 48 KiB
  int tid = threadIdx.x, lane = tid & 63, wave = tid >> 6;
  int wm = wave / WNS, wn = wave % WNS;
  int m0 = blockIdx.x * BM, n0 = blockIdx.y * BN;
  size_t bz = blockIdx.z;
  const us* gA = Aall + bz * aBatch + (size_t)m0 * sAe;
  const us* gB = Ball + bz * bBatch + (size_t)n0 * sBe;
  size_t sA = (size_t)sAe * 2, sB = (size_t)sBe * 2;

  // prologue: tiles 0,1 fully staged (6 loads each)
  stageR<BM, 0, 6>(lds[0], gA, sA, gB, sB, wave, lane);
  stageR<BM, 0, 6>(lds[1], gA + 64, sA, gB + 64, sB, wave, lane);

  int r15 = lane & 15, kg = lane >> 4, l7 = lane & 7;
  int x0 = (kg ^ l7) << 4;          // swizzled k-byte, slice 0
  f32x4 acc[4][4] = {};

  for (int t = 0; t < nt; ++t) {
    if (t == nt - 1) wait_vm0(); else wait_vm6();
    sbar();   // all waves' tile-t staging complete & prior reads done
    const us* buf = lds[t % 3];
    us* nbuf = lds[(t + 2) % 3];
    bool dostage = (t + 2 < nt);
    const us* gA2 = gA + (size_t)(t + 2) * 64;
    const us* gB2 = gB + (size_t)(t + 2) * 64;
    const char* pa = (const char*)buf + (wm * 64 + r15) * 128;
    const char* pb = (const char*)buf + (BM + wn * 64 + r15) * 128;

    // ---- phase 0 (k-slice 0) ----
    if (dostage) stageR<BM, 0, 3>(nbuf, gA2, sA, gB2, sB, wave, lane);
    bf16x8 A0[4], B0[4];
#pragma unroll
    for (int f = 0; f < 4; ++f) A0[f] = *(const bf16x8*)(pa + f * 2048 + x0);
#pragma unroll
    for (int f = 0; f < 4; ++f) B0[f] = *(const bf16x8*)(pb + f * 2048 + x0);
    __builtin_amdgcn_s_setprio(1);
#pragma unroll
    for (int fn = 0; fn < 4; ++fn)
#pragma unroll
      for (int fm = 0; fm < 4; ++fm)
        acc[fm][fn] = __builtin_amdgcn_mfma_f32_16x16x32_bf16(A0[fm], B0[fn], acc[fm][fn], 0, 0, 0);
    __builtin_amdgcn_s_setprio(0);

    // ---- phase 1 (k-slice 1) ----
    if (dostage) stageR<BM, 3, 6>(nbuf, gA2, sA, gB2, sB, wave, lane);
    bf16x8 A1[4], B1[4];
#pragma unroll
    for (int f = 0; f < 4; ++f) A1[f] = *(const bf16x8*)(pa + f * 2048 + (x0 ^ 64));
#pragma unroll
    for (int f = 0; f < 4; ++f) B1[f] = *(const bf16x8*)(pb + f * 2048 + (x0 ^ 64));
    __builtin_amdgcn_s_setprio(1);
#pragma unroll
    for (int fn = 0; fn < 4; ++fn)
#pragma unroll
      for (int fm = 0; fm < 4; ++fm)
        acc[fm][fn] = __builtin_amdgcn_mfma_f32_16x16x32_bf16(A1[fm], B1[fn], acc[fm][fn], 0, 0, 0);
    __builtin_amdgcn_s_setprio(0);
  }

#pragma unroll
  for (int fm = 0; fm < 4; ++fm)
#pragma unroll
    for (int fn = 0; fn < 4; ++fn) {
      int col = n0 + wn * 64 + fn * 16 + r15;
      int row0 = m0 + wm * 64 + fm * 16 + ((lane >> 4) << 2);
      if constexpr (EPI == 0) {
        int mat = col >> 10;
        const float* bp = (mat == 0) ? bq : (mat == 1) ? bk : bv;
        float bb = bp[col & 1023];
        us* ob = (us*)outp + ((size_t)mat << 23);
#pragma unroll
        for (int r = 0; r < 4; ++r)
          ob[(size_t)(row0 + r) * D_ + (col & 1023)] = f2bf(acc[fm][fn][r] + bb);
      } else if constexpr (EPI == 1) {
        _Float16* sc = (_Float16*)outp + bz * (size_t)(S_ * S_);
#pragma unroll
        for (int r = 0; r < 4; ++r)
          sc[(size_t)(row0 + r) * S_ + col] = (_Float16)(acc[fm][fn][r] * 0.03125f);
      } else {
        float* ob = (float*)outp + bz * (size_t)(S_ * D_);
#pragma unroll
        for (int r = 0; r < 4; ++r)
          ob[(size_t)(row0 + r) * D_ + col] = acc[fm][fn][r];
      }
    }
}

// ---------------- W [k][n] fp32 -> Wt bf16 [n][k] (n = mat*1024 + col) ----------------
__global__ __launch_bounds__(256) void wt_prep(const float* __restrict__ Wq,
                                               const float* __restrict__ Wk,
                                               const float* __restrict__ Wv,
                                               us* __restrict__ wtb) {
  __shared__ us hs[64][65];
  int mat = blockIdx.z;
  const float* W = (mat == 0) ? Wq : (mat == 1) ? Wk : Wv;
  int n0 = blockIdx.x * 64, k0 = blockIdx.y * 64;
  int tid = threadIdx.x;
#pragma unroll
  for (int i = 0; i < 16; ++i) {
    int idx = tid + i * 256;
    int r = idx >> 6, c = idx & 63;  // r: k, c: n
    hs[r][c] = f2bf(W[(size_t)(k0 + r) * D_ + (n0 + c)]);
  }
  __syncthreads();
  us* o = wtb + ((size_t)mat << 20);
#pragma unroll
  for (int i = 0; i < 16; ++i) {
    int idx = tid + i * 256;
    int r = idx >> 6, c = idx & 63;  // r: n, c: k
    o[(size_t)(n0 + r) * D_ + (k0 + c)] = hs[c][r];
  }
}

// ---------------- x fp32 -> xb bf16 (same [m][k] layout) ----------------
__global__ __launch_bounds__(256) void xcast(const float* __restrict__ x,
                                             us* __restrict__ xb) {
  size_t i = ((size_t)blockIdx.x * 256 + threadIdx.x) * 8;
  float4 f0 = *(const float4*)(x + i);
  float4 f1 = *(const float4*)(x + i + 4);
  float vals[8] = {f0.x, f0.y, f0.z, f0.w, f1.x, f1.y, f1.z, f1.w};
  union { bf16x8 v; us s_[8]; } H;
#pragma unroll
  for (int e = 0; e < 8; ++e) H.s_[e] = f2bf(vals[e]);
  *(bf16x8*)(xb + i) = H.v;
}

// ---------------- v [b][t][d] -> vT [b][d][t] ----------------
__global__ __launch_bounds__(256) void vtrans(const us* __restrict__ vin,
                                              us* __restrict__ vout) {
  int b = blockIdx.z;
  const us* vi = vin + (size_t)b * S_ * D_;
  us* vo = vout + (size_t)b * D_ * S_;
  int d0 = blockIdx.x * 64, t0 = blockIdx.y * 64;
  __shared__ us ts[64][72];
  int tid = threadIdx.x;
#pragma unroll
  for (int i = 0; i < 16; ++i) {
    int idx = tid + i * 256;
    int r = idx >> 6, c = idx & 63;  // r: t, c: d
    ts[r][c] = vi[(size_t)(t0 + r) * D_ + d0 + c];
  }
  __syncthreads();
#pragma unroll
  for (int i = 0; i < 16; ++i) {
    int idx = tid + i * 256;
    int r = idx >> 6, c = idx & 63;  // r: d, c: t
    vo[(size_t)(d0 + r) * S_ + t0 + c] = ts[c][r];
  }
}

// ---------------- row softmax: fp16 scores -> P bf16 ----------------
__global__ __launch_bounds__(256) void softmax_k(const _Float16* __restrict__ scores,
                                                 us* __restrict__ pb) {
  int row = blockIdx.x, tid = threadIdx.x, lane = tid & 63, wave = tid >> 6;
  const _Float16* s = scores + (size_t)row * S_;
  h4 a4 = ((const h4*)s)[tid];
  h4 b4 = ((const h4*)s)[256 + tid];
  float a[8] = {(float)a4.x, (float)a4.y, (float)a4.z, (float)a4.w,
                (float)b4.x, (float)b4.y, (float)b4.z, (float)b4.w};
  float m = a[0];
#pragma unroll
  for (int e = 1; e < 8; ++e) m = fmaxf(m, a[e]);
#pragma unroll
  for (int o = 32; o; o >>= 1) m = fmaxf(m, __shfl_xor(m, o));
  __shared__ float red[4];
  if (lane == 0) red[wave] = m;
  __syncthreads();
  m = fmaxf(fmaxf(red[0], red[1]), fmaxf(red[2], red[3]));
  float p[8];
  float sum = 0.f;
#pragma unroll
  for (int e = 0; e < 8; ++e) { p[e] = expf(a[e] - m); sum += p[e]; }
#pragma unroll
  for (int o = 32; o; o >>= 1) sum += __shfl_xor(sum, o);
  __syncthreads();  // all reads of red done before reuse
  if (lane == 0) red[wave] = sum;
  __syncthreads();
  float inv = 1.0f / (red[0] + red[1] + red[2] + red[3]);
  us h[8];
#pragma unroll
  for (int e = 0; e < 8; ++e) h[e] = f2bf(p[e] * inv);
  size_t base = (size_t)row * S_;
  *(us4*)(pb + base + tid * 4) = (us4){h[0], h[1], h[2], h[3]};
  *(us4*)(pb + base + 1024 + tid * 4) = (us4){h[4], h[5], h[6], h[7]};
}

extern "C" void kernel_launch(void* const* d_in, const int* in_sizes, int n_in,
                              void* d_out, int out_size, void* d_ws, size_t ws_size,
                              hipStream_t stream) {
  const float* x  = (const float*)d_in[0];
  const float* Wq = (const float*)d_in[1];
  const float* bq = (const float*)d_in[2];
  const float* Wk = (const float*)d_in[3];
  const float* bk = (const float*)d_in[4];
  const float* Wv = (const float*)d_in[5];
  const float* bv = (const float*)d_in[6];
  float* out = (float*)d_out;
  char* ws = (char*)d_ws;
  const size_t MB = 1024 * 1024;
  // Layout (134 MiB; qb/kb/vtmp contiguous = qkv output base):
  //  [0,16)  qb   [16,32) kb   [32,48) vtmp
  //  [48,54) wtb  [54,70) xb   [70,86) vtb
  //  [86,118) scores fp16      [118,134) pb
  us* qb   = (us*)(ws + 0 * MB);
  us* kb   = (us*)(ws + 16 * MB);
  us* vtmp = (us*)(ws + 32 * MB);
  us* wtb  = (us*)(ws + 48 * MB);
  us* xb   = (us*)(ws + 54 * MB);
  us* vtb  = (us*)(ws + 70 * MB);
  _Float16* scores = (_Float16*)(ws + 86 * MB);
  us* pb   = (us*)(ws + 118 * MB);
  (void)vtmp;

  wt_prep<<<dim3(16, 16, 3), 256, 0, stream>>>(Wq, Wk, Wv, wtb);
  xcast<<<dim3(4096), 256, 0, stream>>>(x, xb);
  // qkv: M=8192 x N=3072 (3 mats) x K=1024 -> 768 blocks (3 exact rounds)
  gemm8p<0, 128, 256, 2, 4><<<dim3(64, 12, 1), 512, 0, stream>>>(
      xb, wtb, 0, 0, D_, D_, 16, bq, bk, bv, qb);
  vtrans<<<dim3(16, 32, 4), 256, 0, stream>>>(vtmp, vtb);
  // s2: per batch M=2048 x N=2048 x K=1024 -> 512 blocks (2 rounds)
  gemm8p<1, 128, 256, 2, 4><<<dim3(16, 8, 4), 512, 0, stream>>>(
      qb, kb, (size_t)S_ * D_, (size_t)S_ * D_, D_, D_, 16,
      nullptr, nullptr, nullptr, scores);
  softmax_k<<<dim3(B_ * S_), 256, 0, stream>>>(scores, pb);
  // s3: per batch M=2048 x N=1024 x K=2048, 256x128 tiles -> 256 blocks (1 round)
  gemm8p<2, 256, 128, 4, 2><<<dim3(8, 8, 4), 512, 0, stream>>>(
      pb, vtb, (size_t)S_ * S_, (size_t)D_ * S_, S_, S_, 32,
      nullptr, nullptr, nullptr, out);
}